// Round 1
// baseline (752.259 us; speedup 1.0000x reference)
//
#include <hip/hip_runtime.h>
#include <math.h>

#define BB 4
#define SS 1024
#define DD 1024
#define NH 16
#define DKH 64

// ---------------------------------------------------------------------------
// Kernel 1: wo_mean[k] = mean over rows of Wo[:,k];  bo_mean = mean(bo)
// grid: 16 blocks x 256 threads; each block covers 64 columns.
// ---------------------------------------------------------------------------
__global__ __launch_bounds__(256) void prep_means(const float* __restrict__ Wo,
                                                  const float* __restrict__ bo,
                                                  float* __restrict__ wo_mean,
                                                  float* __restrict__ bo_mean) {
  __shared__ float red[4][64];
  const int tid = threadIdx.x;
  const int c = tid & 63;   // column within this block's 64
  const int g = tid >> 6;   // row group 0..3 (256 rows each)
  const int col = blockIdx.x * 64 + c;
  float s0 = 0.f, s1 = 0.f, s2 = 0.f, s3 = 0.f;
  const float* p = Wo + (size_t)(g * 256) * DD + col;
  for (int r = 0; r < 256; r += 4) {
    s0 += p[(size_t)(r + 0) * DD];
    s1 += p[(size_t)(r + 1) * DD];
    s2 += p[(size_t)(r + 2) * DD];
    s3 += p[(size_t)(r + 3) * DD];
  }
  red[g][c] = (s0 + s1) + (s2 + s3);
  __syncthreads();
  if (g == 0) {
    wo_mean[col] = (red[0][c] + red[1][c] + red[2][c] + red[3][c]) * (1.0f / 1024.0f);
  }
  if (blockIdx.x == 0 && tid < 64) {
    float s = 0.f;
    for (int i = tid; i < 1024; i += 64) s += bo[i];
#pragma unroll
    for (int off = 1; off < 64; off <<= 1) s += __shfl_xor(s, off);
    if (tid == 0) *bo_mean = s * (1.0f / 1024.0f);
  }
}

// ---------------------------------------------------------------------------
// Kernel 2: C = A @ W^T + bias  for the three QKV projections (blockIdx.z).
// A: [4096,1024] row-major, W: [1024,1024] row-major (Linear weight).
// Tile 128x128, BK=16, 256 threads, 8x8 micro-tile (split 64-offset halves).
// ---------------------------------------------------------------------------
__global__ __launch_bounds__(256) void gemm_qkv(
    const float* __restrict__ Xq, const float* __restrict__ Xk, const float* __restrict__ Xv,
    const float* __restrict__ Wq, const float* __restrict__ Wk, const float* __restrict__ Wv,
    const float* __restrict__ bq, const float* __restrict__ bk, const float* __restrict__ bv,
    float* __restrict__ Cq, float* __restrict__ Ck, float* __restrict__ Cv) {
  const int z = blockIdx.z;
  const float* A    = (z == 0) ? Xq : (z == 1) ? Xk : Xv;
  const float* W    = (z == 0) ? Wq : (z == 1) ? Wk : Wv;
  const float* bias = (z == 0) ? bq : (z == 1) ? bk : bv;
  float* C          = (z == 0) ? Cq : (z == 1) ? Ck : Cv;

  __shared__ float As[16][128];
  __shared__ float Bs[16][128];

  const int tid = threadIdx.x;
  const int tx = tid & 15;
  const int ty = tid >> 4;
  const int m0 = blockIdx.y * 128;
  const int n0 = blockIdx.x * 128;

  // staging: thread loads one float4 of A-tile and W-tile rows {srow, srow+64}
  const int srow = tid >> 2;         // 0..63
  const int skq = (tid & 3) << 2;    // 0,4,8,12

  const float* Ap = A + (size_t)(m0 + srow) * DD + skq;
  const float* Wp = W + (size_t)(n0 + srow) * DD + skq;

  float acc[2][2][4][4];
#pragma unroll
  for (int bm = 0; bm < 2; ++bm)
#pragma unroll
    for (int bn = 0; bn < 2; ++bn)
#pragma unroll
      for (int r = 0; r < 4; ++r)
#pragma unroll
        for (int c = 0; c < 4; ++c) acc[bm][bn][r][c] = 0.f;

  for (int k0 = 0; k0 < DD; k0 += 16) {
    const float4 a0 = *(const float4*)(Ap + k0);
    const float4 a1 = *(const float4*)(Ap + (size_t)64 * DD + k0);
    const float4 w0 = *(const float4*)(Wp + k0);
    const float4 w1 = *(const float4*)(Wp + (size_t)64 * DD + k0);
    __syncthreads();  // previous iteration's LDS reads are done
    As[skq + 0][srow] = a0.x; As[skq + 1][srow] = a0.y;
    As[skq + 2][srow] = a0.z; As[skq + 3][srow] = a0.w;
    As[skq + 0][srow + 64] = a1.x; As[skq + 1][srow + 64] = a1.y;
    As[skq + 2][srow + 64] = a1.z; As[skq + 3][srow + 64] = a1.w;
    Bs[skq + 0][srow] = w0.x; Bs[skq + 1][srow] = w0.y;
    Bs[skq + 2][srow] = w0.z; Bs[skq + 3][srow] = w0.w;
    Bs[skq + 0][srow + 64] = w1.x; Bs[skq + 1][srow + 64] = w1.y;
    Bs[skq + 2][srow + 64] = w1.z; Bs[skq + 3][srow + 64] = w1.w;
    __syncthreads();
#pragma unroll
    for (int k = 0; k < 16; ++k) {
      const float4 av0 = *(const float4*)&As[k][ty * 4];
      const float4 av1 = *(const float4*)&As[k][64 + ty * 4];
      const float4 bv0 = *(const float4*)&Bs[k][tx * 4];
      const float4 bv1 = *(const float4*)&Bs[k][64 + tx * 4];
      const float ar[2][4] = {{av0.x, av0.y, av0.z, av0.w},
                              {av1.x, av1.y, av1.z, av1.w}};
      const float br[2][4] = {{bv0.x, bv0.y, bv0.z, bv0.w},
                              {bv1.x, bv1.y, bv1.z, bv1.w}};
#pragma unroll
      for (int bm = 0; bm < 2; ++bm)
#pragma unroll
        for (int bn = 0; bn < 2; ++bn)
#pragma unroll
          for (int r = 0; r < 4; ++r)
#pragma unroll
            for (int c = 0; c < 4; ++c)
              acc[bm][bn][r][c] = fmaf(ar[bm][r], br[bn][c], acc[bm][bn][r][c]);
    }
  }

#pragma unroll
  for (int bn = 0; bn < 2; ++bn) {
    const float4 b4 = *(const float4*)(bias + n0 + bn * 64 + tx * 4);
#pragma unroll
    for (int bm = 0; bm < 2; ++bm)
#pragma unroll
      for (int r = 0; r < 4; ++r) {
        float4 o;
        o.x = acc[bm][bn][r][0] + b4.x;
        o.y = acc[bm][bn][r][1] + b4.y;
        o.z = acc[bm][bn][r][2] + b4.z;
        o.w = acc[bm][bn][r][3] + b4.w;
        *(float4*)(C + (size_t)(m0 + bm * 64 + ty * 4 + r) * DD + n0 + bn * 64 + tx * 4) = o;
      }
  }
}

// ---------------------------------------------------------------------------
// Kernel 3: flash attention per (q-tile 64, head, batch). Online softmax.
// Q/K staged transposed in LDS (stride 66 -> float2 reads, low conflicts).
// ---------------------------------------------------------------------------
__global__ __launch_bounds__(256) void flash_attn(
    const float* __restrict__ Q, const float* __restrict__ K,
    const float* __restrict__ V, const int* __restrict__ mask,
    float* __restrict__ X) {
  __shared__ float Qt[64][66];
  __shared__ float Kt[64][66];
  __shared__ float Vs[64][64];
  __shared__ float Ps[64][68];

  const int tid = threadIdx.x;
  const int tx = tid & 15;
  const int ty = tid >> 4;
  const int q0 = blockIdx.x * 64;
  const int h = blockIdx.y;
  const int b = blockIdx.z;

  const float* Qb = Q + ((size_t)(b * SS + q0)) * DD + h * DKH;
  const float* Kb = K + ((size_t)(b * SS)) * DD + h * DKH;
  const float* Vb = V + ((size_t)(b * SS)) * DD + h * DKH;
  const int* Mb = mask + (size_t)b * SS * SS;

  // stage Q tile transposed: Qt[d][i] = Q[q0+i][d]
#pragma unroll
  for (int p = 0; p < 4; ++p) {
    const int i = p * 16 + ty;
    const float4 q4 = *(const float4*)(Qb + (size_t)i * DD + tx * 4);
    Qt[tx * 4 + 0][i] = q4.x;
    Qt[tx * 4 + 1][i] = q4.y;
    Qt[tx * 4 + 2][i] = q4.z;
    Qt[tx * 4 + 3][i] = q4.w;
  }

  float m_run[4], l_run[4], O[4][4];
#pragma unroll
  for (int r = 0; r < 4; ++r) {
    m_run[r] = -INFINITY;
    l_run[r] = 0.f;
#pragma unroll
    for (int c = 0; c < 4; ++c) O[r][c] = 0.f;
  }

  for (int t = 0; t < 16; ++t) {
    const int k0 = t * 64;
    __syncthreads();  // prior iter reads of Kt/Vs/Ps done (also covers Qt staging)
#pragma unroll
    for (int p = 0; p < 4; ++p) {
      const int j = p * 16 + ty;
      const float4 k4 = *(const float4*)(Kb + (size_t)(k0 + j) * DD + tx * 4);
      Kt[tx * 4 + 0][j] = k4.x;
      Kt[tx * 4 + 1][j] = k4.y;
      Kt[tx * 4 + 2][j] = k4.z;
      Kt[tx * 4 + 3][j] = k4.w;
      const float4 v4 = *(const float4*)(Vb + (size_t)(k0 + j) * DD + tx * 4);
      *(float4*)&Vs[j][tx * 4] = v4;
    }
    __syncthreads();

    // scores tile 64x64: rows i=ty*4+r, cols j=tx*4+c, dot over d
    float s[4][4];
#pragma unroll
    for (int r = 0; r < 4; ++r)
#pragma unroll
      for (int c = 0; c < 4; ++c) s[r][c] = 0.f;
#pragma unroll 8
    for (int d = 0; d < 64; ++d) {
      const float2 qa = *(const float2*)&Qt[d][ty * 4];
      const float2 qb2 = *(const float2*)&Qt[d][ty * 4 + 2];
      const float2 ka = *(const float2*)&Kt[d][tx * 4];
      const float2 kb2 = *(const float2*)&Kt[d][tx * 4 + 2];
      const float qv[4] = {qa.x, qa.y, qb2.x, qb2.y};
      const float kv[4] = {ka.x, ka.y, kb2.x, kb2.y};
#pragma unroll
      for (int r = 0; r < 4; ++r)
#pragma unroll
        for (int c = 0; c < 4; ++c) s[r][c] = fmaf(qv[r], kv[c], s[r][c]);
    }

    // scale + mask + online softmax (row groups = 16 contiguous lanes)
#pragma unroll
    for (int r = 0; r < 4; ++r) {
      const int qrow = q0 + ty * 4 + r;
      const int4 mk = *(const int4*)(Mb + (size_t)qrow * SS + k0 + tx * 4);
      float sr[4];
      sr[0] = (mk.x != 0) ? s[r][0] * 0.125f : -1e9f;
      sr[1] = (mk.y != 0) ? s[r][1] * 0.125f : -1e9f;
      sr[2] = (mk.z != 0) ? s[r][2] * 0.125f : -1e9f;
      sr[3] = (mk.w != 0) ? s[r][3] * 0.125f : -1e9f;
      float mt = fmaxf(fmaxf(sr[0], sr[1]), fmaxf(sr[2], sr[3]));
#pragma unroll
      for (int off = 1; off < 16; off <<= 1) mt = fmaxf(mt, __shfl_xor(mt, off));
      const float m_new = fmaxf(m_run[r], mt);
      const float alpha = __expf(m_run[r] - m_new);  // exp(-inf)=0 on first tile
      float pv[4];
      pv[0] = __expf(sr[0] - m_new);
      pv[1] = __expf(sr[1] - m_new);
      pv[2] = __expf(sr[2] - m_new);
      pv[3] = __expf(sr[3] - m_new);
      float rs = (pv[0] + pv[1]) + (pv[2] + pv[3]);
#pragma unroll
      for (int off = 1; off < 16; off <<= 1) rs += __shfl_xor(rs, off);
      l_run[r] = l_run[r] * alpha + rs;
      m_run[r] = m_new;
      O[r][0] *= alpha; O[r][1] *= alpha; O[r][2] *= alpha; O[r][3] *= alpha;
      *(float4*)&Ps[ty * 4 + r][tx * 4] = make_float4(pv[0], pv[1], pv[2], pv[3]);
    }
    __syncthreads();

    // O[i][dv] += sum_j P[i][j] * V[j][dv]
#pragma unroll 4
    for (int j0 = 0; j0 < 64; j0 += 4) {
      const float4 v0 = *(const float4*)&Vs[j0 + 0][tx * 4];
      const float4 v1 = *(const float4*)&Vs[j0 + 1][tx * 4];
      const float4 v2 = *(const float4*)&Vs[j0 + 2][tx * 4];
      const float4 v3 = *(const float4*)&Vs[j0 + 3][tx * 4];
#pragma unroll
      for (int r = 0; r < 4; ++r) {
        const float4 pr = *(const float4*)&Ps[ty * 4 + r][j0];
        O[r][0] = fmaf(pr.x, v0.x, O[r][0]);
        O[r][1] = fmaf(pr.x, v0.y, O[r][1]);
        O[r][2] = fmaf(pr.x, v0.z, O[r][2]);
        O[r][3] = fmaf(pr.x, v0.w, O[r][3]);
        O[r][0] = fmaf(pr.y, v1.x, O[r][0]);
        O[r][1] = fmaf(pr.y, v1.y, O[r][1]);
        O[r][2] = fmaf(pr.y, v1.z, O[r][2]);
        O[r][3] = fmaf(pr.y, v1.w, O[r][3]);
        O[r][0] = fmaf(pr.z, v2.x, O[r][0]);
        O[r][1] = fmaf(pr.z, v2.y, O[r][1]);
        O[r][2] = fmaf(pr.z, v2.z, O[r][2]);
        O[r][3] = fmaf(pr.z, v2.w, O[r][3]);
        O[r][0] = fmaf(pr.w, v3.x, O[r][0]);
        O[r][1] = fmaf(pr.w, v3.y, O[r][1]);
        O[r][2] = fmaf(pr.w, v3.z, O[r][2]);
        O[r][3] = fmaf(pr.w, v3.w, O[r][3]);
      }
    }
  }

  // normalize and write X[b, q0+i, h*64+dv]
#pragma unroll
  for (int r = 0; r < 4; ++r) {
    const float inv = 1.0f / l_run[r];
    const float4 o = make_float4(O[r][0] * inv, O[r][1] * inv, O[r][2] * inv, O[r][3] * inv);
    *(float4*)(X + ((size_t)(b * SS + q0 + ty * 4 + r)) * DD + h * DKH + tx * 4) = o;
  }
}

// ---------------------------------------------------------------------------
// Kernel 4: in-place epilogue on d_out:
//   xt = threshold(x, 0.2); x1 = dot(xt, wo_mean) + bo_mean; out = xt + x1
// one block per row (4096 rows), 256 threads, 4 floats/thread.
// ---------------------------------------------------------------------------
__global__ __launch_bounds__(256) void epilogue_kernel(float* __restrict__ X,
                                                       const float* __restrict__ wo_mean,
                                                       const float* __restrict__ bo_mean) {
  __shared__ float red[4];
  const int row = blockIdx.x;
  const int tid = threadIdx.x;
  float* xr = X + (size_t)row * DD;
  const float4 x = *(const float4*)(xr + tid * 4);
  const float4 w = *(const float4*)(wo_mean + tid * 4);
  float4 xt;
  xt.x = (x.x > 0.2f) ? x.x : 0.f;
  xt.y = (x.y > 0.2f) ? x.y : 0.f;
  xt.z = (x.z > 0.2f) ? x.z : 0.f;
  xt.w = (x.w > 0.2f) ? x.w : 0.f;
  float part = xt.x * w.x + xt.y * w.y + xt.z * w.z + xt.w * w.w;
#pragma unroll
  for (int off = 1; off < 64; off <<= 1) part += __shfl_xor(part, off);
  if ((tid & 63) == 0) red[tid >> 6] = part;
  __syncthreads();
  const float x1 = (red[0] + red[1]) + (red[2] + red[3]) + *bo_mean;
  const float4 o = make_float4(xt.x + x1, xt.y + x1, xt.z + x1, xt.w + x1);
  *(float4*)(xr + tid * 4) = o;
}

// ---------------------------------------------------------------------------
extern "C" void kernel_launch(void* const* d_in, const int* in_sizes, int n_in,
                              void* d_out, int out_size, void* d_ws, size_t ws_size,
                              hipStream_t stream) {
  const float* query = (const float*)d_in[0];
  const float* key = (const float*)d_in[1];
  const float* value = (const float*)d_in[2];
  const int* mask = (const int*)d_in[3];
  const float* Wq = (const float*)d_in[4];
  const float* bq = (const float*)d_in[5];
  const float* Wk = (const float*)d_in[6];
  const float* bk = (const float*)d_in[7];
  const float* Wv = (const float*)d_in[8];
  const float* bv = (const float*)d_in[9];
  const float* Wo = (const float*)d_in[10];
  const float* bo = (const float*)d_in[11];

  float* ws = (float*)d_ws;
  float* Q = ws;                      // 4096x1024
  float* K = ws + 4194304;            // 4096x1024
  float* V = ws + 8388608;            // 4096x1024
  float* wo_mean = ws + 12582912;     // 1024
  float* bo_mean = wo_mean + 1024;    // 1
  float* X = (float*)d_out;           // attention output lives in d_out, epilogue is in-place

  prep_means<<<16, 256, 0, stream>>>(Wo, bo, wo_mean, bo_mean);

  dim3 gg(DD / 128, 4096 / 128, 3);
  gemm_qkv<<<gg, 256, 0, stream>>>(query, key, value, Wq, Wk, Wv, bq, bk, bv, Q, K, V);

  dim3 ga(SS / 64, NH, BB);
  flash_attn<<<ga, 256, 0, stream>>>(Q, K, V, mask, X);

  epilogue_kernel<<<4096, 256, 0, stream>>>(X, wo_mean, bo_mean);
}

// Round 2
// 269.888 us; speedup vs baseline: 2.7873x; 2.7873x over previous
//
#include <hip/hip_runtime.h>
#include <hip/hip_bf16.h>
#include <math.h>

#define BB 4
#define SS 1024
#define DD 1024
#define NH 16
#define DKH 64

typedef __attribute__((ext_vector_type(8))) short bf16x8;   // MFMA A/B frag (4 VGPRs)
typedef __attribute__((ext_vector_type(4))) float f32x4;    // MFMA C/D frag

__device__ __forceinline__ ushort f2bf(float f) {
  __hip_bfloat16 h = __float2bfloat16(f);
  return *(ushort*)&h;
}

__device__ __forceinline__ bf16x8 pack8(float4 a, float4 b) {
  bf16x8 r;
  r[0] = (short)f2bf(a.x); r[1] = (short)f2bf(a.y);
  r[2] = (short)f2bf(a.z); r[3] = (short)f2bf(a.w);
  r[4] = (short)f2bf(b.x); r[5] = (short)f2bf(b.y);
  r[6] = (short)f2bf(b.z); r[7] = (short)f2bf(b.w);
  return r;
}

// ---------------------------------------------------------------------------
// wo_mean / bo_mean (unchanged from passing round — keeps output bit-identical)
// ---------------------------------------------------------------------------
__global__ __launch_bounds__(256) void prep_means(const float* __restrict__ Wo,
                                                  const float* __restrict__ bo,
                                                  float* __restrict__ wo_mean,
                                                  float* __restrict__ bo_mean) {
  __shared__ float red[4][64];
  const int tid = threadIdx.x;
  const int c = tid & 63;
  const int g = tid >> 6;
  const int col = blockIdx.x * 64 + c;
  float s0 = 0.f, s1 = 0.f, s2 = 0.f, s3 = 0.f;
  const float* p = Wo + (size_t)(g * 256) * DD + col;
  for (int r = 0; r < 256; r += 4) {
    s0 += p[(size_t)(r + 0) * DD];
    s1 += p[(size_t)(r + 1) * DD];
    s2 += p[(size_t)(r + 2) * DD];
    s3 += p[(size_t)(r + 3) * DD];
  }
  red[g][c] = (s0 + s1) + (s2 + s3);
  __syncthreads();
  if (g == 0) {
    wo_mean[col] = (red[0][c] + red[1][c] + red[2][c] + red[3][c]) * (1.0f / 1024.0f);
  }
  if (blockIdx.x == 0 && tid < 64) {
    float s = 0.f;
    for (int i = tid; i < 1024; i += 64) s += bo[i];
#pragma unroll
    for (int off = 1; off < 64; off <<= 1) s += __shfl_xor(s, off);
    if (tid == 0) *bo_mean = s * (1.0f / 1024.0f);
  }
}

// ---------------------------------------------------------------------------
// Convert Wq/Wk/Wv fp32 -> bf16 (weights only; activations convert in-GEMM)
// ---------------------------------------------------------------------------
__global__ __launch_bounds__(256) void convert_w(const float* __restrict__ Wq,
                                                 const float* __restrict__ Wk,
                                                 const float* __restrict__ Wv,
                                                 ushort* __restrict__ Wb) {
  const int z = blockIdx.y;
  const float* W = (z == 0) ? Wq : (z == 1) ? Wk : Wv;
  const size_t i = ((size_t)blockIdx.x * 256 + threadIdx.x) * 4;
  const float4 f = *(const float4*)(W + i);
  ushort4 u;
  u.x = f2bf(f.x); u.y = f2bf(f.y); u.z = f2bf(f.z); u.w = f2bf(f.w);
  *(ushort4*)(Wb + (size_t)z * 1048576 + i) = u;
}

// ---------------------------------------------------------------------------
// maskOK[(b*8+qt)*16+kt] = 1 iff the whole 128x64 mask tile is nonzero
// ---------------------------------------------------------------------------
__global__ __launch_bounds__(256) void mask_ok_kernel(const int* __restrict__ mask,
                                                      int* __restrict__ maskOK) {
  const int kt = blockIdx.x, qt = blockIdx.y, b = blockIdx.z;
  const int tid = threadIdx.x;
  const int row = tid >> 1, half = tid & 1;
  const int* p = mask + ((size_t)b * SS + qt * 128 + row) * SS + kt * 64 + half * 32;
  int ok = 1;
#pragma unroll
  for (int j = 0; j < 8; ++j) {
    const int4 m = *(const int4*)(p + j * 4);
    ok &= (m.x != 0) & (m.y != 0) & (m.z != 0) & (m.w != 0);
  }
  const unsigned long long bal = __ballot(ok);
  __shared__ int red[4];
  if ((tid & 63) == 0) red[tid >> 6] = (bal == ~0ULL) ? 1 : 0;
  __syncthreads();
  if (tid == 0) maskOK[(b * 8 + qt) * 16 + kt] = red[0] & red[1] & red[2] & red[3];
}

// ---------------------------------------------------------------------------
// bf16 MFMA GEMM: C = A @ W^T (+bias) -> bf16, scale folded for z==0 (Q/8).
// 128x128 tile, BK=32, 256 threads (4 waves as 2x2 of 64x64).
// Operand swap: mfma(Wfrag, Afrag, acc) => lane holds 4 consecutive C-cols.
// ---------------------------------------------------------------------------
__global__ __launch_bounds__(256) void gemm_qkv_bf16(
    const float* __restrict__ Xq, const float* __restrict__ Xk, const float* __restrict__ Xv,
    const ushort* __restrict__ Wb,
    const float* __restrict__ bq, const float* __restrict__ bk, const float* __restrict__ bv,
    ushort* __restrict__ QKVb) {
  const int z = blockIdx.z;
  const float* A = (z == 0) ? Xq : (z == 1) ? Xk : Xv;
  const ushort* Wz = Wb + (size_t)z * 1048576;
  const float* bias = (z == 0) ? bq : (z == 1) ? bk : bv;
  ushort* Cz = QKVb + (size_t)z * 4194304;
  const float sc = (z == 0) ? 0.125f : 1.0f;

  __shared__ ushort As[128 * 32];
  __shared__ ushort Ws[128 * 32];

  const int tid = threadIdx.x;
  const int lane = tid & 63, w = tid >> 6;
  const int quad = lane >> 4, l15 = lane & 15;
  const int wn = w & 1, wm = w >> 1;
  const int n0 = blockIdx.x * 128, m0 = blockIdx.y * 128;

  // staging ids: thread covers 16 elements of row (tid>>1), k-half (tid&1)*16
  const int ar = tid >> 1;
  const int ak = (tid & 1) * 16;
  const float* Ap = A + (size_t)(m0 + ar) * DD + ak;
  const ushort* Wp = Wz + (size_t)(n0 + ar) * DD + ak;
  ushort* AsP = &As[ar * 32 + ak];
  ushort* WsP = &Ws[ar * 32 + ak];

  f32x4 acc[4][4];
  const f32x4 z4 = {0.f, 0.f, 0.f, 0.f};
#pragma unroll
  for (int mt = 0; mt < 4; ++mt)
#pragma unroll
    for (int nt = 0; nt < 4; ++nt) acc[mt][nt] = z4;

  for (int k0 = 0; k0 < DD; k0 += 32) {
    const float4 a0 = *(const float4*)(Ap + k0);
    const float4 a1 = *(const float4*)(Ap + k0 + 4);
    const float4 a2 = *(const float4*)(Ap + k0 + 8);
    const float4 a3 = *(const float4*)(Ap + k0 + 12);
    const uint4 w0 = *(const uint4*)(Wp + k0);
    const uint4 w1 = *(const uint4*)(Wp + k0 + 8);
    __syncthreads();  // previous iteration's frag reads done
    *(bf16x8*)(AsP) = pack8(a0, a1);
    *(bf16x8*)(AsP + 8) = pack8(a2, a3);
    *(uint4*)(WsP) = w0;
    *(uint4*)(WsP + 8) = w1;
    __syncthreads();  // tile visible
    bf16x8 wf[4], af[4];
#pragma unroll
    for (int nt = 0; nt < 4; ++nt)
      wf[nt] = *(const bf16x8*)&Ws[(wn * 64 + nt * 16 + l15) * 32 + quad * 8];
#pragma unroll
    for (int mt = 0; mt < 4; ++mt)
      af[mt] = *(const bf16x8*)&As[(wm * 64 + mt * 16 + l15) * 32 + quad * 8];
#pragma unroll
    for (int mt = 0; mt < 4; ++mt)
#pragma unroll
      for (int nt = 0; nt < 4; ++nt)
        acc[mt][nt] = __builtin_amdgcn_mfma_f32_16x16x32_bf16(wf[nt], af[mt], acc[mt][nt], 0, 0, 0);
  }

  // epilogue: bias + scale, pack 4 consecutive cols (reg dim) per store
#pragma unroll
  for (int nt = 0; nt < 4; ++nt) {
    const float4 b4 = *(const float4*)(bias + n0 + wn * 64 + nt * 16 + quad * 4);
#pragma unroll
    for (int mt = 0; mt < 4; ++mt) {
      const f32x4 v = acc[mt][nt];
      ushort4 pk;
      pk.x = f2bf((v[0] + b4.x) * sc);
      pk.y = f2bf((v[1] + b4.y) * sc);
      pk.z = f2bf((v[2] + b4.z) * sc);
      pk.w = f2bf((v[3] + b4.w) * sc);
      *(ushort4*)&Cz[(size_t)(m0 + wm * 64 + mt * 16 + l15) * DD + n0 + wn * 64 + nt * 16 + quad * 4] = pk;
    }
  }
}

// ---------------------------------------------------------------------------
// MFMA flash attention. Block = (q-tile 128, head, batch); 4 waves x 32 q-rows.
// Computes S^T = K·Q^T so lane's col (lane&15) = its q-row: softmax per-lane.
// PV as O^T = V^T·P^T; O regs = 4 consecutive d -> float4 stores.
// Scale 1/8 pre-folded into Q by the GEMM.
// ---------------------------------------------------------------------------
__global__ __launch_bounds__(256) void flash_mfma(
    const ushort* __restrict__ QKVb, const int* __restrict__ mask,
    const int* __restrict__ maskOK, float* __restrict__ X) {
  __shared__ ushort Vt[64 * 72];   // Vt[d][key], padded
  __shared__ ushort Ps[128 * 72];  // Ps[q_local][key], padded

  const ushort* Qb = QKVb;
  const ushort* Kb = QKVb + 4194304;
  const ushort* Vb = QKVb + 8388608;

  const int tid = threadIdx.x;
  const int lane = tid & 63, w = tid >> 6;
  const int quad = lane >> 4, l15 = lane & 15;
  const int qblk = blockIdx.x, h = blockIdx.y, b = blockIdx.z;
  const int qbase = qblk * 128 + w * 32;

  // Q fragments (B-operand), register-resident for all 16 K-tiles
  bf16x8 qf[2][2];
#pragma unroll
  for (int qt = 0; qt < 2; ++qt)
#pragma unroll
    for (int ks = 0; ks < 2; ++ks)
      qf[qt][ks] = *(const bf16x8*)(Qb + (size_t)(b * SS + qbase + qt * 16 + l15) * DD +
                                    h * DKH + ks * 32 + quad * 8);

  f32x4 o[4][2];
  const f32x4 z4 = {0.f, 0.f, 0.f, 0.f};
#pragma unroll
  for (int dt = 0; dt < 4; ++dt)
#pragma unroll
    for (int qt = 0; qt < 2; ++qt) o[dt][qt] = z4;
  float m_run[2] = {-INFINITY, -INFINITY};
  float l_run[2] = {0.f, 0.f};

  const int vp = tid & 31;   // key pair index
  const int vdc = tid >> 5;  // d-chunk (8 dims)
  const ushort* Vg = Vb + (size_t)(b * SS) * DD + h * DKH + vdc * 8;
  uint* VtU = (uint*)Vt;
  const int* Mb = mask + (size_t)b * SS * SS;

  for (int kt = 0; kt < 16; ++kt) {
    const int k064 = kt * 64;
    __syncthreads();  // prior iteration's Vt/Ps reads complete
    // stage V transposed: pack (key 2p, 2p+1) pairs -> conflict-free b32 writes
    union { uint4 u; ushort s[8]; } v0, v1;
    v0.u = *(const uint4*)(Vg + (size_t)(k064 + 2 * vp) * DD);
    v1.u = *(const uint4*)(Vg + (size_t)(k064 + 2 * vp + 1) * DD);
#pragma unroll
    for (int j = 0; j < 8; ++j)
      VtU[(vdc * 8 + j) * 36 + vp] = (uint)v0.s[j] | ((uint)v1.s[j] << 16);
    // K fragments (A-operand) straight from global (L1/L2-hot)
    bf16x8 kf[4][2];
#pragma unroll
    for (int mt = 0; mt < 4; ++mt)
#pragma unroll
      for (int ks = 0; ks < 2; ++ks)
        kf[mt][ks] = *(const bf16x8*)(Kb + (size_t)(b * SS + k064 + mt * 16 + l15) * DD +
                                      h * DKH + ks * 32 + quad * 8);
    __syncthreads();  // Vt visible

    // S^T tiles: rows = keys (quad*4+reg), col = q (lane&15)
    f32x4 s[4][2];
#pragma unroll
    for (int mt = 0; mt < 4; ++mt)
#pragma unroll
      for (int qt = 0; qt < 2; ++qt) {
        f32x4 a = z4;
        a = __builtin_amdgcn_mfma_f32_16x16x32_bf16(kf[mt][0], qf[qt][0], a, 0, 0, 0);
        a = __builtin_amdgcn_mfma_f32_16x16x32_bf16(kf[mt][1], qf[qt][1], a, 0, 0, 0);
        s[mt][qt] = a;
      }

    // mask (fast path: whole tile all-ones -> skip)
    const int ok = maskOK[(b * 8 + qblk) * 16 + kt];
    if (!ok) {
#pragma unroll
      for (int mt = 0; mt < 4; ++mt)
#pragma unroll
        for (int qt = 0; qt < 2; ++qt)
#pragma unroll
          for (int reg = 0; reg < 4; ++reg) {
            const int q = qbase + qt * 16 + l15;
            const int key = k064 + mt * 16 + quad * 4 + reg;
            if (Mb[(size_t)q * SS + key] == 0) s[mt][qt][reg] = -1e9f;
          }
    }

    // online softmax per q-column (this lane's q = qbase + qt*16 + l15)
#pragma unroll
    for (int qt = 0; qt < 2; ++qt) {
      float mx = s[0][qt][0];
#pragma unroll
      for (int mt = 0; mt < 4; ++mt)
#pragma unroll
        for (int reg = 0; reg < 4; ++reg) mx = fmaxf(mx, s[mt][qt][reg]);
      mx = fmaxf(mx, __shfl_xor(mx, 16));
      mx = fmaxf(mx, __shfl_xor(mx, 32));
      const float m_new = fmaxf(m_run[qt], mx);
      const float alpha = __expf(m_run[qt] - m_new);
      float rs = 0.f;
#pragma unroll
      for (int mt = 0; mt < 4; ++mt) {
#pragma unroll
        for (int reg = 0; reg < 4; ++reg) {
          const float p = __expf(s[mt][qt][reg] - m_new);
          s[mt][qt][reg] = p;
          rs += p;
        }
      }
      rs += __shfl_xor(rs, 16);
      rs += __shfl_xor(rs, 32);
      l_run[qt] = l_run[qt] * alpha + rs;
      m_run[qt] = m_new;
#pragma unroll
      for (int dt = 0; dt < 4; ++dt) o[dt][qt] *= alpha;
      // write P^T: lane holds 4 consecutive keys at its q -> one b64 per tile
#pragma unroll
      for (int mt = 0; mt < 4; ++mt) {
        ushort4 pk;
        pk.x = f2bf(s[mt][qt][0]);
        pk.y = f2bf(s[mt][qt][1]);
        pk.z = f2bf(s[mt][qt][2]);
        pk.w = f2bf(s[mt][qt][3]);
        *(ushort4*)&Ps[(w * 32 + qt * 16 + l15) * 72 + mt * 16 + quad * 4] = pk;
      }
    }

    // O^T += V^T · P^T  (Ps rows are wave-local; compiler orders the LDS dep)
    bf16x8 pf[2][2];
#pragma unroll
    for (int qt = 0; qt < 2; ++qt)
#pragma unroll
      for (int ks = 0; ks < 2; ++ks)
        pf[qt][ks] = *(const bf16x8*)&Ps[(w * 32 + qt * 16 + l15) * 72 + ks * 32 + quad * 8];
#pragma unroll
    for (int dt = 0; dt < 4; ++dt) {
      bf16x8 vf0 = *(const bf16x8*)&Vt[(dt * 16 + l15) * 72 + quad * 8];
      bf16x8 vf1 = *(const bf16x8*)&Vt[(dt * 16 + l15) * 72 + 32 + quad * 8];
#pragma unroll
      for (int qt = 0; qt < 2; ++qt) {
        o[dt][qt] = __builtin_amdgcn_mfma_f32_16x16x32_bf16(vf0, pf[qt][0], o[dt][qt], 0, 0, 0);
        o[dt][qt] = __builtin_amdgcn_mfma_f32_16x16x32_bf16(vf1, pf[qt][1], o[dt][qt], 0, 0, 0);
      }
    }
  }

  // normalize + store: lane holds 4 consecutive d -> coalescable float4
#pragma unroll
  for (int qt = 0; qt < 2; ++qt) {
    const float inv = 1.0f / l_run[qt];
#pragma unroll
    for (int dt = 0; dt < 4; ++dt) {
      const f32x4 ov = o[dt][qt] * inv;
      *(f32x4*)(X + (size_t)(b * SS + qbase + qt * 16 + l15) * DD +
                h * DKH + dt * 16 + quad * 4) = ov;
    }
  }
}

// ---------------------------------------------------------------------------
// Epilogue (unchanged): xt = threshold(x,0.2); out = xt + dot(xt,wo_mean)+bo_mean
// ---------------------------------------------------------------------------
__global__ __launch_bounds__(256) void epilogue_kernel(float* __restrict__ X,
                                                       const float* __restrict__ wo_mean,
                                                       const float* __restrict__ bo_mean) {
  __shared__ float red[4];
  const int row = blockIdx.x;
  const int tid = threadIdx.x;
  float* xr = X + (size_t)row * DD;
  const float4 x = *(const float4*)(xr + tid * 4);
  const float4 w = *(const float4*)(wo_mean + tid * 4);
  float4 xt;
  xt.x = (x.x > 0.2f) ? x.x : 0.f;
  xt.y = (x.y > 0.2f) ? x.y : 0.f;
  xt.z = (x.z > 0.2f) ? x.z : 0.f;
  xt.w = (x.w > 0.2f) ? x.w : 0.f;
  float part = xt.x * w.x + xt.y * w.y + xt.z * w.z + xt.w * w.w;
#pragma unroll
  for (int off = 1; off < 64; off <<= 1) part += __shfl_xor(part, off);
  if ((tid & 63) == 0) red[tid >> 6] = part;
  __syncthreads();
  const float x1 = (red[0] + red[1]) + (red[2] + red[3]) + *bo_mean;
  const float4 o = make_float4(xt.x + x1, xt.y + x1, xt.z + x1, xt.w + x1);
  *(float4*)(xr + tid * 4) = o;
}

// ---------------------------------------------------------------------------
extern "C" void kernel_launch(void* const* d_in, const int* in_sizes, int n_in,
                              void* d_out, int out_size, void* d_ws, size_t ws_size,
                              hipStream_t stream) {
  const float* query = (const float*)d_in[0];
  const float* key = (const float*)d_in[1];
  const float* value = (const float*)d_in[2];
  const int* mask = (const int*)d_in[3];
  const float* Wq = (const float*)d_in[4];
  const float* bq = (const float*)d_in[5];
  const float* Wk = (const float*)d_in[6];
  const float* bk = (const float*)d_in[7];
  const float* Wv = (const float*)d_in[8];
  const float* bv = (const float*)d_in[9];
  const float* Wo = (const float*)d_in[10];
  const float* bo = (const float*)d_in[11];

  // workspace layout (~31.5 MB)
  ushort* Wb = (ushort*)d_ws;                    // 3 x 1048576 bf16
  ushort* QKVb = Wb + 3 * 1048576;               // 3 x 4194304 bf16
  float* wo_mean = (float*)(QKVb + (size_t)3 * 4194304);
  float* bo_mean = wo_mean + 1024;
  int* maskOK = (int*)(bo_mean + 1);             // 512 ints
  float* X = (float*)d_out;

  prep_means<<<16, 256, 0, stream>>>(Wo, bo, wo_mean, bo_mean);
  convert_w<<<dim3(1024, 3), 256, 0, stream>>>(Wq, Wk, Wv, Wb);
  mask_ok_kernel<<<dim3(16, 8, 4), 256, 0, stream>>>(mask, maskOK);

  gemm_qkv_bf16<<<dim3(8, 32, 3), 256, 0, stream>>>(query, key, value, Wb, bq, bk, bv, QKVb);

  flash_mfma<<<dim3(8, 16, 4), 256, 0, stream>>>(QKVb, mask, maskOK, X);

  epilogue_kernel<<<4096, 256, 0, stream>>>(X, wo_mean, bo_mean);
}